// Round 4
// baseline (85.376 us; speedup 1.0000x reference)
//
#include <hip/hip_runtime.h>
#include <hip/hip_cooperative_groups.h>
#include <math.h>

namespace cg = cooperative_groups;

#define NBINS  512
#define TPB    512
#define GBLKS  256   // 1 block/CU -> co-resident, grid.sync() is safe

// Single cooperative kernel, one graph node, no memset.
// Phase 1: one thread per gaussian; walk only the active bin range
//   [blo, bhi] (pdf == 0 left of the zero crossing due to the lower clamp;
//   < 6e-13 beyond 7.5 sigma; upper clamp never binds) and scatter into a
//   per-block LDS histogram via ds_add_f32. Flush PRE-SCALED (x 1/r^2,
//   linearity) partials to d_ws with coalesced plain stores.
// grid.sync()
// Phase 2: block b reduces bins {2b, 2b+1} across the 256 partials and
//   plain-stores d_out (every element written every call -> poison-safe).
__global__ __launch_bounds__(TPB) void gauss_fused_coop(
    const float* __restrict__ means,
    const float* __restrict__ scan_point,
    const float* __restrict__ colours,
    const float* __restrict__ coefficients,
    const float* __restrict__ opacities,
    const float* __restrict__ pre_act,
    const int*   __restrict__ view_id_p,
    float* __restrict__ partial,   // [GBLKS][NBINS] in d_ws
    float* __restrict__ out,       // NBINS floats
    int n)
{
    __shared__ float hist[NBINS];
    const int tid = threadIdx.x;
    hist[tid] = 0.0f;
    __syncthreads();

    for (int i = blockIdx.x * TPB + tid; i < n; i += GBLKS * TPB) {
        const int vid = view_id_p[0];
        const float op  = opacities[i + vid];      // (N,1)[:, view_id]
        const float col = colours[i];
        const float inten = (1.0f / (1.0f + __expf(-op))) * col * col;
        const float cf    = 1.0f / (1.0f + __expf(-coefficients[i]));

        const float dx = means[3*i]   - scan_point[0];
        const float dy = means[3*i+1] - scan_point[1];
        const float dz = means[3*i+2] - scan_point[2];
        const float r0 = sqrtf(fmaf(dx, dx, fmaf(dy, dy, dz*dz)));

        const float sigma = fmaxf(__expf(pre_act[i]), 0.005f);

        // e = (r - r0) * q, with q chosen so g = exp2(-e^2)
        const float q  = 0.8493218002880191f / sigma;  // sqrt(0.5*log2(e))/sigma
        const float c  = inten * 0.005f;               // fold intensity + BIN_RES/2
        const float A2 = c * cf * 0.3989422804014327f / sigma;
        const float B3 = c * (1.0f - cf) / (0.8493218002880191f * sigma);

        // active range: pdf >= 0 for r >= r0 - (cf/(1-cf))*0.39894*sigma,
        // negligible for r > r0 + 7.5*sigma. r_[b] = 0.005*(b+1).
        const float rlo = r0 - (cf / (1.0f - cf)) * 0.3989422804014327f * sigma;
        const float rhi = r0 + 7.5f * sigma;
        int blo = (int)ceilf(rlo * 200.0f - 1.0f);
        int bhi = (int)floorf(rhi * 200.0f - 1.0f);
        blo = max(blo, 0);
        bhi = min(bhi, NBINS - 1);

        float e = (0.005f * (float)(blo + 1) - r0) * q;
        const float de = 0.005f * q;
        for (int b = blo; b <= bhi; ++b) {
            const float g = __builtin_amdgcn_exp2f(-(e * e));
            const float t = g * fmaf(B3, e, A2);   // inten*pr
            unsafeAtomicAdd(&hist[b], t);          // ds_add_f32
            e += de;
        }
    }
    __syncthreads();

    // coalesced pre-scaled flush: partial[block][bin] = hist[bin] / r_bin^2
    {
        const float r = 0.005f * (float)(tid + 1);
        partial[blockIdx.x * NBINS + tid] = hist[tid] / (r * r);
    }
    __threadfence();              // device-scope: make d_ws visible cross-XCD
    cg::this_grid().sync();

    // Phase 2: threads 0-255 -> bin 2b, threads 256-511 -> bin 2b+1.
    const int half = tid >> 8;                 // 0 or 1
    const int bin  = blockIdx.x * 2 + half;
    const int g    = tid & 255;
    float s = partial[g * NBINS + bin];

    #pragma unroll
    for (int off = 32; off > 0; off >>= 1)
        s += __shfl_down(s, off, 64);

    __shared__ float wsum[8];
    if ((tid & 63) == 0) wsum[tid >> 6] = s;
    __syncthreads();
    if ((tid & 255) == 0) {
        const int base = half * 4;
        out[bin] = wsum[base] + wsum[base + 1] + wsum[base + 2] + wsum[base + 3];
    }
}

extern "C" void kernel_launch(void* const* d_in, const int* in_sizes, int n_in,
                              void* d_out, int out_size, void* d_ws, size_t ws_size,
                              hipStream_t stream) {
    const float* means        = (const float*)d_in[0];
    const float* scan_point   = (const float*)d_in[1];
    const float* colours      = (const float*)d_in[2];
    const float* coefficients = (const float*)d_in[3];
    const float* opacities    = (const float*)d_in[4];
    const float* pre_act      = (const float*)d_in[5];
    const int*   view_id      = (const int*)d_in[6];

    int n = in_sizes[2];                       // colours has N elements
    float* partial = (float*)d_ws;             // GBLKS*NBINS*4 = 512 KB
    float* out     = (float*)d_out;

    void* args[] = {
        (void*)&means, (void*)&scan_point, (void*)&colours,
        (void*)&coefficients, (void*)&opacities, (void*)&pre_act,
        (void*)&view_id, (void*)&partial, (void*)&out, (void*)&n
    };
    hipLaunchCooperativeKernel((const void*)gauss_fused_coop,
                               dim3(GBLKS), dim3(TPB), args, 0, stream);
}